// Round 1
// baseline (193.453 us; speedup 1.0000x reference)
//
#include <hip/hip_runtime.h>

#define DDIM 1024
#define NEXP 64
#define TOPK 8
#define ROWS_PER_BLOCK 128
#define TAU 2e-3f

typedef __attribute__((ext_vector_type(8))) short short8;
typedef __attribute__((ext_vector_type(4))) float f32x4;

static __device__ __forceinline__ unsigned int f2u(float f) { return __builtin_bit_cast(unsigned int, f); }
static __device__ __forceinline__ float u2f(unsigned int u) { return __builtin_bit_cast(float, u); }

// f32 -> bf16 round-to-nearest-even (bits)
static __device__ __forceinline__ unsigned short bf_hi_rne(float x) {
    unsigned int u = f2u(x);
    return (unsigned short)((u + (0x7FFFu + ((u >> 16) & 1u))) >> 16);
}

// f32 -> (hi = RNE bf16, lo = trunc bf16 of exact residual).  |x - hi - lo| <= 2^-17 |x|
static __device__ __forceinline__ void split2(float x, unsigned short& h, unsigned short& l) {
    unsigned int u = f2u(x);
    unsigned int uh = (u + (0x7FFFu + ((u >> 16) & 1u))) & 0xFFFF0000u;
    h = (unsigned short)(uh >> 16);
    float rem = x - u2f(uh);          // exact in f32
    l = (unsigned short)(f2u(rem) >> 16);
}

static __device__ __forceinline__ void make_frags(const float* __restrict__ p, short8& h8, short8& l8) {
    f32x4 a = ((const f32x4*)p)[0];
    f32x4 b = ((const f32x4*)p)[1];
#pragma unroll
    for (int i = 0; i < 4; i++) { unsigned short h, l; split2(a[i], h, l); h8[i] = (short)h; l8[i] = (short)l; }
#pragma unroll
    for (int i = 0; i < 4; i++) { unsigned short h, l; split2(b[i], h, l); h8[i + 4] = (short)h; l8[i + 4] = (short)l; }
}

static __device__ __forceinline__ short8 make_hi8(const float* __restrict__ p) {
    f32x4 a = ((const f32x4*)p)[0];
    f32x4 b = ((const f32x4*)p)[1];
    short8 r;
#pragma unroll
    for (int i = 0; i < 4; i++) r[i] = (short)bf_hi_rne(a[i]);
#pragma unroll
    for (int i = 0; i < 4; i++) r[i + 4] = (short)bf_hi_rne(b[i]);
    return r;
}

// Prologue: convert Wn -> (hi,lo) bf16, We -> hi bf16, into workspace.
__global__ __launch_bounds__(256) void conv_w_kernel(
    const float* __restrict__ Wn, const float* __restrict__ We,
    unsigned short* __restrict__ wn_hi, unsigned short* __restrict__ wn_lo,
    unsigned short* __restrict__ we_hi)
{
    int i = blockIdx.x * 256 + threadIdx.x;   // 0 .. 65535
    unsigned short h, l;
    split2(Wn[i], h, l);
    wn_hi[i] = h;
    wn_lo[i] = l;
    we_hi[i] = bf_hi_rne(We[i]);
}

// Main fused kernel: router (split-bf16 MFMA, ~1e-5 accurate) + expert GEMV (bf16-hi MFMA)
// + per-row top-8 / softmax / weighted-sum epilogue + fp64 fixup for near-tie rows.
template <int PRE>
__global__ __launch_bounds__(256, 2) void moe_kernel(
    const float* __restrict__ x, const float* __restrict__ Wn,
    const float* __restrict__ bn, const float* __restrict__ We,
    const unsigned short* __restrict__ wn_hi, const unsigned short* __restrict__ wn_lo,
    const unsigned short* __restrict__ we_hi, float* __restrict__ out)
{
    __shared__ float s_log[ROWS_PER_BLOCK][NEXP + 1];
    __shared__ float s_exp[ROWS_PER_BLOCK][NEXP + 1];
    __shared__ float s_vb[ROWS_PER_BLOCK];

    const int tid = threadIdx.x;
    const int wid = tid >> 6;          // wave 0..3
    const int lane = tid & 63;
    const int fr = lane & 15;          // A-row / B-col within 16-tile
    const int fq = lane >> 4;          // k-chunk quadrant
    const int blockRow = blockIdx.x * ROWS_PER_BLOCK;
    const int wrow = blockRow + wid * 32;   // this wave's 32 rows

    f32x4 accN[2][4];   // router accumulators  [rowtile][coltile]
    f32x4 accE[2][4];   // expert accumulators
#pragma unroll
    for (int rt = 0; rt < 2; rt++)
#pragma unroll
        for (int ct = 0; ct < 4; ct++) {
            accN[rt][ct] = f32x4{0.f, 0.f, 0.f, 0.f};
            accE[rt][ct] = f32x4{0.f, 0.f, 0.f, 0.f};
        }

    const float* xp0 = x + (size_t)(wrow + fr) * DDIM + fq * 8;
    const float* xp1 = xp0 + (size_t)16 * DDIM;

    // 1-deep x prefetch (HBM latency)
    f32x4 px00 = ((const f32x4*)xp0)[0], px01 = ((const f32x4*)xp0)[1];
    f32x4 px10 = ((const f32x4*)xp1)[0], px11 = ((const f32x4*)xp1)[1];

    for (int k0 = 0; k0 < DDIM; k0 += 32) {
        short8 ah[2], al[2];
#pragma unroll
        for (int i = 0; i < 4; i++) { unsigned short h, l; split2(px00[i], h, l); ah[0][i] = (short)h; al[0][i] = (short)l; }
#pragma unroll
        for (int i = 0; i < 4; i++) { unsigned short h, l; split2(px01[i], h, l); ah[0][i + 4] = (short)h; al[0][i + 4] = (short)l; }
#pragma unroll
        for (int i = 0; i < 4; i++) { unsigned short h, l; split2(px10[i], h, l); ah[1][i] = (short)h; al[1][i] = (short)l; }
#pragma unroll
        for (int i = 0; i < 4; i++) { unsigned short h, l; split2(px11[i], h, l); ah[1][i + 4] = (short)h; al[1][i + 4] = (short)l; }

        const int kn = (k0 + 32 < DDIM) ? (k0 + 32) : k0;   // last iter reloads same chunk (no OOB)
        px00 = ((const f32x4*)(xp0 + kn))[0]; px01 = ((const f32x4*)(xp0 + kn))[1];
        px10 = ((const f32x4*)(xp1 + kn))[0]; px11 = ((const f32x4*)(xp1 + kn))[1];

        const int kk = k0 + fq * 8;
#pragma unroll
        for (int ct = 0; ct < 4; ++ct) {
            short8 wh, wl, eh;
            if constexpr (PRE) {
                const int off = (ct * 16 + fr) * DDIM + kk;
                wh = *(const short8*)(wn_hi + off);
                wl = *(const short8*)(wn_lo + off);
                eh = *(const short8*)(we_hi + off);
            } else {
                const float* wp = Wn + (size_t)(ct * 16 + fr) * DDIM + kk;
                const float* ep = We + (size_t)(ct * 16 + fr) * DDIM + kk;
                make_frags(wp, wh, wl);
                eh = make_hi8(ep);
            }
#pragma unroll
            for (int rt = 0; rt < 2; rt++) {
                accN[rt][ct] = __builtin_amdgcn_mfma_f32_16x16x32_bf16(ah[rt], wh, accN[rt][ct], 0, 0, 0);
                accN[rt][ct] = __builtin_amdgcn_mfma_f32_16x16x32_bf16(ah[rt], wl, accN[rt][ct], 0, 0, 0);
                accN[rt][ct] = __builtin_amdgcn_mfma_f32_16x16x32_bf16(al[rt], wh, accN[rt][ct], 0, 0, 0);
                accE[rt][ct] = __builtin_amdgcn_mfma_f32_16x16x32_bf16(ah[rt], eh, accE[rt][ct], 0, 0, 0);
            }
        }
    }

    // C/D layout (verified m89): col = lane&15, row = (lane>>4)*4 + j
#pragma unroll
    for (int ct = 0; ct < 4; ++ct) {
        const int e = ct * 16 + fr;
        const float be = bn[e];
#pragma unroll
        for (int rt = 0; rt < 2; ++rt) {
#pragma unroll
            for (int j = 0; j < 4; j++) {
                const int rl = wid * 32 + rt * 16 + fq * 4 + j;
                s_log[rl][e] = accN[rt][ct][j] + be;
                s_exp[rl][e] = accE[rt][ct][j];
            }
        }
    }
    __syncthreads();

    const int rl = wid * 32 + (lane & 31);
    const bool owner = (lane < 32);

    auto do_row = [&](int r, float& gapo, float& vbo) -> float {
        float selv[TOPK]; int seli[TOPK];
        unsigned long long chosen = 0ull;
#pragma unroll
        for (int t = 0; t < TOPK; t++) {
            float best = -3.0e38f; int bi = 0;
#pragma unroll 4
            for (int e = 0; e < NEXP; e++) {
                float v = s_log[r][e];
                if (!((chosen >> e) & 1ull) && v > best) { best = v; bi = e; }  // strict > => lowest index on ties
            }
            selv[t] = best; seli[t] = bi; chosen |= (1ull << bi);
        }
        float v9 = -3.0e38f;
#pragma unroll 4
        for (int e = 0; e < NEXP; e++) {
            float v = s_log[r][e];
            if (!((chosen >> e) & 1ull) && v > v9) v9 = v;
        }
        gapo = selv[TOPK - 1] - v9;
        vbo = 0.5f * (selv[TOPK - 1] + v9);
        float m = selv[0], Z = 0.f, o = 0.f;
#pragma unroll
        for (int t = 0; t < TOPK; t++) {
            float w = __expf(selv[t] - m);
            Z += w;
            o += w * s_exp[r][seli[t]];
        }
        return o / Z;
    };

    float gap = 3.0e38f;
    if (owner) {
        float vb;
        float res = do_row(rl, gap, vb);
        out[blockRow + rl] = res;
        s_vb[rl] = vb;
    }
    const bool flagged = owner && (gap < TAU);
    unsigned long long flg = __ballot(flagged);
    __syncthreads();   // s_vb visible; all selection reads done before fixup writes

    // fp64 fixup for near-tie rows: recompute boundary-band candidate logits exactly
    while (flg) {
        const int fl = __builtin_ctzll(flg);
        flg &= flg - 1;
        const int r = wid * 32 + fl;
        const float vbr = s_vb[r];
        const float ve = s_log[r][lane];
        unsigned long long cand = __ballot(fabsf(ve - vbr) <= TAU);
        const f32x4* xq = (const f32x4*)(x + (size_t)(blockRow + r) * DDIM) + lane * 4;
        const f32x4 xv0 = xq[0], xv1 = xq[1], xv2 = xq[2], xv3 = xq[3];
        while (cand) {
            const int e = __builtin_ctzll(cand);
            cand &= cand - 1;
            const f32x4* wq = (const f32x4*)(Wn + (size_t)e * DDIM) + lane * 4;
            const f32x4 w0 = wq[0], w1 = wq[1], w2 = wq[2], w3 = wq[3];
            double s = 0.0;
#pragma unroll
            for (int i = 0; i < 4; i++) s = fma((double)xv0[i], (double)w0[i], s);
#pragma unroll
            for (int i = 0; i < 4; i++) s = fma((double)xv1[i], (double)w1[i], s);
#pragma unroll
            for (int i = 0; i < 4; i++) s = fma((double)xv2[i], (double)w2[i], s);
#pragma unroll
            for (int i = 0; i < 4; i++) s = fma((double)xv3[i], (double)w3[i], s);
#pragma unroll
            for (int off = 32; off > 0; off >>= 1) s += __shfl_xor(s, off);
            s += (double)bn[e];
            if (lane == 0) s_log[r][e] = (float)s;
        }
    }
    __syncthreads();

    if (flagged) {
        float g2, vb2;
        float res = do_row(rl, g2, vb2);
        out[blockRow + rl] = res;
    }
}

extern "C" void kernel_launch(void* const* d_in, const int* in_sizes, int n_in,
                              void* d_out, int out_size, void* d_ws, size_t ws_size,
                              hipStream_t stream)
{
    // setup_inputs order: x, Wg, bg, Wn, bn, We, noise  (Wg/bg/noise are dead code)
    const float* x  = (const float*)d_in[0];
    const float* Wn = (const float*)d_in[3];
    const float* bn = (const float*)d_in[4];
    const float* We = (const float*)d_in[5];
    float* out = (float*)d_out;

    const int B = in_sizes[0] / DDIM;           // 65536
    const int grid = B / ROWS_PER_BLOCK;        // 512

    const size_t need = (size_t)NEXP * DDIM * sizeof(unsigned short) * 3;   // 384 KiB
    if (d_ws != nullptr && ws_size >= need) {
        unsigned short* wn_hi = (unsigned short*)d_ws;
        unsigned short* wn_lo = wn_hi + NEXP * DDIM;
        unsigned short* we_hi = wn_lo + NEXP * DDIM;
        conv_w_kernel<<<(NEXP * DDIM) / 256, 256, 0, stream>>>(Wn, We, wn_hi, wn_lo, we_hi);
        moe_kernel<1><<<grid, 256, 0, stream>>>(x, Wn, bn, We, wn_hi, wn_lo, we_hi, out);
    } else {
        moe_kernel<0><<<grid, 256, 0, stream>>>(x, Wn, bn, We, nullptr, nullptr, nullptr, out);
    }
}

// Round 2
// 110.093 us; speedup vs baseline: 1.7572x; 1.7572x over previous
//
#include <hip/hip_runtime.h>

#define DDIM 1024
#define NEXP 64
#define TOPK 8
#define BK 32
#define ROWS 64
#define NTILE (DDIM / BK)
#define TAU 2e-3f

typedef __attribute__((ext_vector_type(8))) short short8;
typedef __attribute__((ext_vector_type(4))) float f32x4;

static __device__ __forceinline__ unsigned int f2u(float f) { return __builtin_bit_cast(unsigned int, f); }
static __device__ __forceinline__ float u2f(unsigned int u) { return __builtin_bit_cast(float, u); }

// f32 -> bf16 round-to-nearest-even (bits)
static __device__ __forceinline__ unsigned short bf_hi_rne(float x) {
    unsigned int u = f2u(x);
    return (unsigned short)((u + (0x7FFFu + ((u >> 16) & 1u))) >> 16);
}

// f32 -> (hi = RNE bf16, lo = trunc bf16 of exact residual).  |x - hi - lo| <= 2^-17 |x|
static __device__ __forceinline__ void split2(float x, unsigned short& h, unsigned short& l) {
    unsigned int u = f2u(x);
    unsigned int uh = (u + (0x7FFFu + ((u >> 16) & 1u))) & 0xFFFF0000u;
    h = (unsigned short)(uh >> 16);
    float rem = x - u2f(uh);          // exact in f32
    l = (unsigned short)(f2u(rem) >> 16);
}

// Prologue: convert Wn -> (hi,lo) bf16, We -> hi bf16, into workspace.
__global__ __launch_bounds__(256) void conv_w_kernel(
    const float* __restrict__ Wn, const float* __restrict__ We,
    unsigned short* __restrict__ wn_hi, unsigned short* __restrict__ wn_lo,
    unsigned short* __restrict__ we_hi)
{
    int i = blockIdx.x * 256 + threadIdx.x;   // 0 .. 65535
    unsigned short h, l;
    split2(Wn[i], h, l);
    wn_hi[i] = h;
    wn_lo[i] = l;
    we_hi[i] = bf_hi_rne(We[i]);
}

// LDS map (40960 B total -> 4 blocks/CU):
//   xbuf[b] : b*8192      .. +8192   (xhi [64][32]bf16 4KB, xlo 4KB), swizzled
//   wbuf[b] : 16384+b*12288 .. +12288 (wn_hi 4KB, wn_lo 4KB, we_hi 4KB), swizzled
//   epilogue reuse: s_log [64][65]f32 @0, s_exp [64][65]f32 @16640, s_vb @33280
// Swizzle (both tiles are [64 rows][32 elems] bf16, 64B rows):
//   byte = (row*64 + chunk*16) ^ ((row&7)<<4)   -- bijective, 2-way-bank-optimal.
template <int PRE>
__global__ __launch_bounds__(256, 4) void moe_kernel(
    const float* __restrict__ x, const float* __restrict__ Wn,
    const float* __restrict__ bn, const float* __restrict__ We,
    const unsigned short* __restrict__ wn_hi, const unsigned short* __restrict__ wn_lo,
    const unsigned short* __restrict__ we_hi, float* __restrict__ out)
{
    __shared__ __align__(16) char smem[40960];

    const int tid = threadIdx.x;
    const int wid = tid >> 6;          // wave 0..3  (expert-column tile)
    const int lane = tid & 63;
    const int fr = lane & 15;
    const int fq = lane >> 4;
    const int blockRow = blockIdx.x * ROWS;

    // ---- staging role: thread handles x row srow, 8-float group sg; W row e=srow, chunk sg
    const int srow = tid >> 2, sg = tid & 3;
    const int swz = (srow * 64 + sg * 16) ^ ((srow & 7) << 4);
    const float* xsrc = x + (size_t)(blockRow + srow) * DDIM + sg * 8;

    f32x4 sx0, sx1;                  // x staging regs (8 floats)
    short8 sw0, sw1, sw2;            // W staging regs (PRE path)
    f32x4 sn0, sn1, se0, se1;        // W staging regs (fallback f32 path)

    auto stage_load = [&](int t) {
        const int k0 = t * BK;
        sx0 = *(const f32x4*)(xsrc + k0);
        sx1 = *(const f32x4*)(xsrc + k0 + 4);
        if constexpr (PRE) {
            const int woff = srow * DDIM + k0 + sg * 8;
            sw0 = *(const short8*)(wn_hi + woff);
            sw1 = *(const short8*)(wn_lo + woff);
            sw2 = *(const short8*)(we_hi + woff);
        } else {
            const float* np = Wn + (size_t)srow * DDIM + k0 + sg * 8;
            const float* ep = We + (size_t)srow * DDIM + k0 + sg * 8;
            sn0 = ((const f32x4*)np)[0]; sn1 = ((const f32x4*)np)[1];
            se0 = ((const f32x4*)ep)[0]; se1 = ((const f32x4*)ep)[1];
        }
    };

    auto stage_write = [&](int b) {
        short8 xh, xl;
#pragma unroll
        for (int i = 0; i < 4; i++) { unsigned short h, l; split2(sx0[i], h, l); xh[i] = (short)h; xl[i] = (short)l; }
#pragma unroll
        for (int i = 0; i < 4; i++) { unsigned short h, l; split2(sx1[i], h, l); xh[i + 4] = (short)h; xl[i + 4] = (short)l; }
        char* xb = smem + b * 8192 + swz;
        *(short8*)(xb) = xh;
        *(short8*)(xb + 4096) = xl;
        char* wb = smem + 16384 + b * 12288 + swz;
        if constexpr (PRE) {
            *(short8*)(wb) = sw0;
            *(short8*)(wb + 4096) = sw1;
            *(short8*)(wb + 8192) = sw2;
        } else {
            short8 nh, nl, eh8;
#pragma unroll
            for (int i = 0; i < 4; i++) { unsigned short h, l; split2(sn0[i], h, l); nh[i] = (short)h; nl[i] = (short)l; }
#pragma unroll
            for (int i = 0; i < 4; i++) { unsigned short h, l; split2(sn1[i], h, l); nh[i + 4] = (short)h; nl[i + 4] = (short)l; }
#pragma unroll
            for (int i = 0; i < 4; i++) eh8[i] = (short)bf_hi_rne(se0[i]);
#pragma unroll
            for (int i = 0; i < 4; i++) eh8[i + 4] = (short)bf_hi_rne(se1[i]);
            *(short8*)(wb) = nh;
            *(short8*)(wb + 4096) = nl;
            *(short8*)(wb + 8192) = eh8;
        }
    };

    // ---- accumulators: this wave owns experts wid*16+fr, all 64 rows (4 row-tiles)
    f32x4 accN[4], accE[4];
#pragma unroll
    for (int rt = 0; rt < 4; rt++) { accN[rt] = f32x4{0.f,0.f,0.f,0.f}; accE[rt] = f32x4{0.f,0.f,0.f,0.f}; }

    const int ecol = wid * 16 + fr;
    const int woffr = (ecol * 64 + fq * 16) ^ ((ecol & 7) << 4);

    auto compute = [&](int b) {
        const char* xb = smem + b * 8192;
        const char* wb = smem + 16384 + b * 12288;
        short8 wh = *(const short8*)(wb + woffr);
        short8 wl = *(const short8*)(wb + 4096 + woffr);
        short8 eh = *(const short8*)(wb + 8192 + woffr);
#pragma unroll
        for (int rt = 0; rt < 4; rt++) {
            const int row = rt * 16 + fr;
            const int xoff = (row * 64 + fq * 16) ^ ((row & 7) << 4);
            short8 xh = *(const short8*)(xb + xoff);
            short8 xl = *(const short8*)(xb + 4096 + xoff);
            accN[rt] = __builtin_amdgcn_mfma_f32_16x16x32_bf16(xh, wh, accN[rt], 0, 0, 0);
            accN[rt] = __builtin_amdgcn_mfma_f32_16x16x32_bf16(xh, wl, accN[rt], 0, 0, 0);
            accN[rt] = __builtin_amdgcn_mfma_f32_16x16x32_bf16(xl, wh, accN[rt], 0, 0, 0);
            accE[rt] = __builtin_amdgcn_mfma_f32_16x16x32_bf16(xh, eh, accE[rt], 0, 0, 0);
        }
    };

    // ---- pipelined main loop: 1 raw barrier per tile, loads 2 tiles in flight
    stage_load(0);
    stage_write(0);                      // compiler inserts vmcnt wait before converts
    stage_load(1);
    asm volatile("s_waitcnt lgkmcnt(0)" ::: "memory");
    __builtin_amdgcn_s_barrier();
    asm volatile("" ::: "memory");

#pragma unroll 2
    for (int t = 0; t < NTILE; ++t) {
        compute(t & 1);
        if (t < NTILE - 1) {
            stage_write((t + 1) & 1);    // regs for tile t+1 (vmcnt auto-waited here)
            if (t + 2 < NTILE) stage_load(t + 2);
            asm volatile("s_waitcnt lgkmcnt(0)" ::: "memory");
            __builtin_amdgcn_s_barrier();
            asm volatile("" ::: "memory");
        }
    }
    __syncthreads();                     // all waves done reading stage buffers

    // ---- epilogue: dump logits/expert-vals to LDS (overlays stage buffers)
    float* s_log = (float*)smem;                 // [64][65]
    float* s_exp = (float*)(smem + 16640);       // [64][65]
    float* s_vb  = (float*)(smem + 33280);       // [64]

    const float be = bn[ecol];
#pragma unroll
    for (int rt = 0; rt < 4; rt++) {
#pragma unroll
        for (int j = 0; j < 4; j++) {
            const int r = rt * 16 + fq * 4 + j;  // C/D layout: col=lane&15, row=(lane>>4)*4+j
            s_log[r * 65 + ecol] = accN[rt][j] + be;
            s_exp[r * 65 + ecol] = accE[rt][j];
        }
    }
    __syncthreads();

    if (wid == 0) {
        // lane owns row `lane` (0..63)
        auto do_row = [&](int r, float& gapo, float& vbo) -> float {
            float selv[TOPK]; int seli[TOPK];
            unsigned long long chosen = 0ull;
#pragma unroll
            for (int t = 0; t < TOPK; t++) {
                float best = -3.0e38f; int bi = 0;
#pragma unroll 4
                for (int e = 0; e < NEXP; e++) {
                    float v = s_log[r * 65 + e];
                    if (!((chosen >> e) & 1ull) && v > best) { best = v; bi = e; }
                }
                selv[t] = best; seli[t] = bi; chosen |= (1ull << bi);
            }
            float v9 = -3.0e38f;
#pragma unroll 4
            for (int e = 0; e < NEXP; e++) {
                float v = s_log[r * 65 + e];
                if (!((chosen >> e) & 1ull) && v > v9) v9 = v;
            }
            gapo = selv[TOPK - 1] - v9;
            vbo = 0.5f * (selv[TOPK - 1] + v9);
            float m = selv[0], Z = 0.f, o = 0.f;
#pragma unroll
            for (int t = 0; t < TOPK; t++) {
                float w = __expf(selv[t] - m);
                Z += w;
                o += w * s_exp[r * 65 + seli[t]];
            }
            return o / Z;
        };

        float gap, vb;
        float res = do_row(lane, gap, vb);
        out[blockRow + lane] = res;
        s_vb[lane] = vb;
        const bool flagged = (gap < TAU);
        unsigned long long flg = __ballot(flagged);

        // fp64 fixup for near-tie rows: recompute boundary-band candidate logits exactly
        while (flg) {
            const int r = __builtin_ctzll(flg);
            flg &= flg - 1;
            const float vbr = s_vb[r];
            const float ve = s_log[r * 65 + lane];
            unsigned long long cand = __ballot(fabsf(ve - vbr) <= TAU);
            const f32x4* xq = (const f32x4*)(x + (size_t)(blockRow + r) * DDIM) + lane * 4;
            const f32x4 xv0 = xq[0], xv1 = xq[1], xv2 = xq[2], xv3 = xq[3];
            while (cand) {
                const int ce = __builtin_ctzll(cand);
                cand &= cand - 1;
                const f32x4* wq = (const f32x4*)(Wn + (size_t)ce * DDIM) + lane * 4;
                const f32x4 w0 = wq[0], w1 = wq[1], w2 = wq[2], w3 = wq[3];
                double s = 0.0;
#pragma unroll
                for (int i = 0; i < 4; i++) s = fma((double)xv0[i], (double)w0[i], s);
#pragma unroll
                for (int i = 0; i < 4; i++) s = fma((double)xv1[i], (double)w1[i], s);
#pragma unroll
                for (int i = 0; i < 4; i++) s = fma((double)xv2[i], (double)w2[i], s);
#pragma unroll
                for (int i = 0; i < 4; i++) s = fma((double)xv3[i], (double)w3[i], s);
#pragma unroll
                for (int off = 32; off > 0; off >>= 1) s += __shfl_xor(s, off);
                s += (double)bn[ce];
                if (lane == 0) s_log[r * 65 + ce] = (float)s;
            }
        }
        if (flagged) {
            float g2, v2;
            out[blockRow + lane] = do_row(lane, g2, v2);
        }
    }
}

extern "C" void kernel_launch(void* const* d_in, const int* in_sizes, int n_in,
                              void* d_out, int out_size, void* d_ws, size_t ws_size,
                              hipStream_t stream)
{
    // setup_inputs order: x, Wg, bg, Wn, bn, We, noise  (Wg/bg/noise are dead code)
    const float* x  = (const float*)d_in[0];
    const float* Wn = (const float*)d_in[3];
    const float* bn = (const float*)d_in[4];
    const float* We = (const float*)d_in[5];
    float* out = (float*)d_out;

    const int B = in_sizes[0] / DDIM;           // 65536
    const int grid = B / ROWS;                  // 1024

    const size_t need = (size_t)NEXP * DDIM * sizeof(unsigned short) * 3;   // 384 KiB
    if (d_ws != nullptr && ws_size >= need) {
        unsigned short* wn_hi = (unsigned short*)d_ws;
        unsigned short* wn_lo = wn_hi + NEXP * DDIM;
        unsigned short* we_hi = wn_lo + NEXP * DDIM;
        conv_w_kernel<<<(NEXP * DDIM) / 256, 256, 0, stream>>>(Wn, We, wn_hi, wn_lo, we_hi);
        moe_kernel<1><<<grid, 256, 0, stream>>>(x, Wn, bn, We, wn_hi, wn_lo, we_hi, out);
    } else {
        moe_kernel<0><<<grid, 256, 0, stream>>>(x, Wn, bn, We, nullptr, nullptr, nullptr, out);
    }
}